// Round 8
// baseline (98.788 us; speedup 1.0000x reference)
//
#include <hip/hip_runtime.h>
#include <stdint.h>

constexpr int L_LEVELS = 16;
constexpr int T_SIZE   = 16384;
constexpr int N_PTS    = 262144;

typedef _Float16 h2 __attribute__((ext_vector_type(2)));
typedef _Float16 h4 __attribute__((ext_vector_type(4)));
typedef _Float16 h8 __attribute__((ext_vector_type(8)));

// Byte-offset-scaled hash constants: prime*4 mod 2^32, mask (T-1)*4.
constexpr uint32_t P1_4 = 2654435761u * 4u;
constexpr uint32_t P2_4 = 805459861u * 4u;
constexpr uint32_t M4   = (T_SIZE - 1) * 4u;   // 65532

__device__ __forceinline__ h2 lerp2(h2 a, h2 b, h2 t) {
    return a + t * (b - a);                     // v_pk_sub + v_pk_fma
}

// ---------------------------------------------------------------------------
// Session ledger:
//  * 256 MiB poison fill (~45 us) is UNCONDITIONAL -> fixed floor; ws free.
//  * Split pipeline (A ~22-30 + B ~9) stuck at dur ~87 across 4 variants:
//    staging format / occupancy / gather-ILP all NEUTRAL.
//  * R2 fused (47 us) lost to split because reg-staging put loads + 64 KB
//    ds_write per level on the critical path between barriers.
//  * R6: (n,l) partial-line scatter = 2x write amp. Full-line stores only.
// This round: single fused kernel, all 16 levels, with staging cost removed:
//  - fp16 tables pre-converted in ws (cvt prepass ~2.5 us, ws is free)
//  - global_load_lds DMA staging (no VGPR roundtrip, no ds_write phase)
//  - 2x64 KB double buffer: DMA(l+1) issued BEFORE level-l gathers into the
//    other buffer (its readers finished at end-of-(l-1) barrier) -> DMA
//    latency hides under gathers; ONE barrier/level (implicit vmcnt(0)).
//  - epilogue reuses dead table LDS for transpose -> full-line f32 stores.
//  - launch_bounds(1024,4): 128 VGPR cap, live state ~45 regs, no spill.
// ---------------------------------------------------------------------------

// Kernel 0: convert f32 tables (L,T,2) -> fp16 h2 tables in ws (1 MiB).
__global__ __launch_bounds__(256) void cvt_tables(
    const float* __restrict__ emb, h2* __restrict__ tbl)
{
    const int i = blockIdx.x * 256 + threadIdx.x;        // 65536 h8 groups
    const float4* __restrict__ s = reinterpret_cast<const float4*>(emb);
    float4 a = s[2 * i];
    float4 b = s[2 * i + 1];
    h8 w = { (_Float16)a.x, (_Float16)a.y, (_Float16)a.z, (_Float16)a.w,
             (_Float16)b.x, (_Float16)b.y, (_Float16)b.z, (_Float16)b.w };
    reinterpret_cast<h8*>(tbl)[i] = w;                   // 16 B store
}

// Kernel 1: fused all-level encode with DMA-staged double-buffered tables.
__global__ __launch_bounds__(1024, 4) void hash_encode_dma(
    const float* __restrict__ x,
    const h2*    __restrict__ tbl,    // (L, T) fp16 feature pairs (ws)
    float4*      __restrict__ out)    // (N, 8 float4) = (N, 32 floats)
{
    __shared__ union {
        h2 tab[2][T_SIZE];            // 2 x 64 KB level double-buffer
        h2 tr[1024][18];              // 72 KB transpose buffer (72 B rows)
    } sm;

    const int t    = threadIdx.x;     // 0..1023
    const int lane = t & 63;
    const int wid  = t >> 6;          // 0..15
    const int n    = blockIdx.x * 1024 + t;

    // Point coords: read once, kept in VGPRs for all 16 levels.
    const float x0 = x[3 * n + 0];
    const float x1 = x[3 * n + 1];
    const float x2 = x[3 * n + 2];

    const char* __restrict__ gt = reinterpret_cast<const char*>(tbl);

    // DMA one 64 KB level table into buffer b: 4 KB per wave = 4 x
    // global_load_lds_dwordx4 (HW: lds dst = uniform base + lane*16;
    // global src is per-lane). LDS layout = linear copy of the table.
    auto stage = [&](int lvl, int b) {
        const char* g = gt + ((size_t)lvl << 16) + (wid << 12) + (lane << 4);
        char* d = reinterpret_cast<char*>(sm.tab[b]) + (wid << 12);
#pragma unroll
        for (int it = 0; it < 4; ++it)
            __builtin_amdgcn_global_load_lds(
                (const __attribute__((address_space(1))) void*)(g + (it << 10)),
                (__attribute__((address_space(3))) void*)(d + (it << 10)),
                16, 0, 0);
    };

    stage(0, 0);
    __syncthreads();                  // drains vmcnt(0): table 0 ready

    union { h2 r[L_LEVELS]; h4 q4[8]; } res;

#pragma unroll
    for (int l = 0; l < L_LEVELS; ++l) {
        // Issue next level's DMA into the other buffer FIRST: its previous
        // readers (level l-1) finished at the end-of-(l-1) barrier, and the
        // transfer flies while we gather from buf[l&1].
        if (l < L_LEVELS - 1) stage(l + 1, (l + 1) & 1);

        // N_l = 16 * 2^(5l/16); constant-folded per unrolled level.
        const float Nl = 16.0f * exp2f((float)l * 0.3125f);
        const char* __restrict__ tb =
            reinterpret_cast<const char*>(sm.tab[l & 1]);

        const float u0 = x0 * Nl, u1 = x1 * Nl, u2 = x2 * Nl;
        // u >= 0: df = u - floor(u); exact-integer case gives df=0 which
        // zeroes the (possibly wrong-slot) hi-corner lerp term -> correct.
        const float fl0 = floorf(u0), fl1 = floorf(u1), fl2 = floorf(u2);
        const float df0 = u0 - fl0, df1 = u1 - fl1, df2 = u2 - fl2;

        // Byte-offset hash products for the lo corner (prime*4, wrapping).
        const uint32_t q0 = ((uint32_t)(int32_t)fl0) << 2;       // prime 1
        const uint32_t q1 = ((uint32_t)(int32_t)fl1) * P1_4;
        const uint32_t q2 = ((uint32_t)(int32_t)fl2) * P2_4;
        // Masked XOR deltas per dim ((a^b)&M4).
        const uint32_t d0 = (q0 ^ (q0 + 4u))   & M4;
        const uint32_t d1 = (q1 ^ (q1 + P1_4)) & M4;
        const uint32_t d2 = (q2 ^ (q2 + P2_4)) & M4;

        uint32_t off = (q0 ^ q1 ^ q2) & M4;     // corner 000 byte offset

        // Gray-code gather order: one XOR per subsequent corner address.
        constexpr int gray[8] = {0, 1, 3, 2, 6, 7, 5, 4};
        h2 f[8];
#pragma unroll
        for (int j = 0; j < 8; ++j) {
            f[gray[j]] = *reinterpret_cast<const h2*>(tb + off);  // ds_read_b32
            if (j < 7) {
                const int tog = gray[j] ^ gray[j + 1];            // 4,2,1
                off ^= (tog == 4) ? d0 : (tog == 2) ? d1 : d2;
            }
        }

        // Packed-fp16 trilinear lerp tree (both features per register).
        const _Float16 h0 = (_Float16)df0, h1 = (_Float16)df1,
                       hv2 = (_Float16)df2;
        const h2 t0 = {h0, h0}, t1 = {h1, h1}, t2 = {hv2, hv2};
        h2 e0 = lerp2(f[0], f[1], t2);
        h2 e1 = lerp2(f[2], f[3], t2);
        h2 e2 = lerp2(f[4], f[5], t2);
        h2 e3 = lerp2(f[6], f[7], t2);
        h2 g0 = lerp2(e0, e1, t1);
        h2 g1 = lerp2(e2, e3, t1);
        res.r[l] = lerp2(g0, g1, t0);

        // One barrier per level: syncs this level's gathers AND (implicit
        // vmcnt(0) drain) guarantees the DMA'd next table is resident.
        __syncthreads();
    }

    // ---- Epilogue: LDS transpose -> lane-contiguous full-line stores ----
    // tab is dead (last barrier passed); tr overlays it. 72 B rows spread
    // banks; h4 (8 B) writes are 8 B-aligned (72 % 8 == 0).
#pragma unroll
    for (int g = 0; g < 8; ++g)          // 8 x ds_write_b64
        *reinterpret_cast<h4*>(&sm.tr[t][2 * g]) = res.q4[g];
    __syncthreads();

    // Thread t, iter i handles flat block-local float4 #(i*1024+t):
    // point p = f>>3, float4-part = f&7 -> levels 2*part, 2*part+1.
    float4* __restrict__ o = out + (size_t)blockIdx.x * 8192;
#pragma unroll
    for (int i = 0; i < 8; ++i) {
        const int f    = i * 1024 + t;
        const int p    = f >> 3;
        const int part = f & 7;
        h4 v = *reinterpret_cast<const h4*>(&sm.tr[p][2 * part]); // ds_read_b64
        o[f] = make_float4((float)v.x, (float)v.y,
                           (float)v.z, (float)v.w);    // 1 KB/instr, full lines
    }
}

// ---------------------------------------------------------------------------
// Fallback (ws too small): R3's workspace-free fused kernel (proven pass).
// ---------------------------------------------------------------------------
__global__ __launch_bounds__(1024, 4) void hash_encode_fused(
    const float* __restrict__ x,
    const float* __restrict__ emb,
    float4*      __restrict__ out)
{
    __shared__ union {
        h2 tab[2][T_SIZE];
        h2 tr[1024][20];
    } sm;

    const int t = threadIdx.x;
    const int n = blockIdx.x * 1024 + t;
    const int rot = (blockIdx.x << 4) & 4095;

    const float x0 = x[3 * n + 0];
    const float x1 = x[3 * n + 1];
    const float x2 = x[3 * n + 2];

    {
        const float4* __restrict__ s = reinterpret_cast<const float4*>(emb);
        h8* __restrict__ d = reinterpret_cast<h8*>(sm.tab[0]);
#pragma unroll
        for (int r = 0; r < 4; ++r) {
            const int j = (r * 1024 + t + rot) & 4095;
            float4 a = s[2 * j];
            float4 b = s[2 * j + 1];
            h8 w = { (_Float16)a.x, (_Float16)a.y, (_Float16)a.z, (_Float16)a.w,
                     (_Float16)b.x, (_Float16)b.y, (_Float16)b.z, (_Float16)b.w };
            d[j] = w;
        }
    }
    __syncthreads();

    union { h2 r[L_LEVELS]; h8 q[4]; } resu;

#pragma unroll
    for (int l = 0; l < L_LEVELS; ++l) {
        float4 sa0, sb0, sa1, sb1, sa2, sb2, sa3, sb3;
        int j0 = 0, j1 = 0, j2 = 0, j3 = 0;
        if (l < L_LEVELS - 1) {
            const float4* __restrict__ s = reinterpret_cast<const float4*>(
                emb + (size_t)(l + 1) * T_SIZE * 2);
            j0 = (0 * 1024 + t + rot) & 4095;
            j1 = (1 * 1024 + t + rot) & 4095;
            j2 = (2 * 1024 + t + rot) & 4095;
            j3 = (3 * 1024 + t + rot) & 4095;
            sa0 = s[2 * j0]; sb0 = s[2 * j0 + 1];
            sa1 = s[2 * j1]; sb1 = s[2 * j1 + 1];
            sa2 = s[2 * j2]; sb2 = s[2 * j2 + 1];
            sa3 = s[2 * j3]; sb3 = s[2 * j3 + 1];
        }

        const float Nl = 16.0f * exp2f((float)l * 0.3125f);
        const char* __restrict__ tb =
            reinterpret_cast<const char*>(sm.tab[l & 1]);

        const float u0 = x0 * Nl, u1 = x1 * Nl, u2 = x2 * Nl;
        const float fl0 = floorf(u0), fl1 = floorf(u1), fl2 = floorf(u2);
        const float df0 = u0 - fl0, df1 = u1 - fl1, df2 = u2 - fl2;

        const uint32_t q0 = ((uint32_t)(int32_t)fl0) << 2;
        const uint32_t q1 = ((uint32_t)(int32_t)fl1) * P1_4;
        const uint32_t q2 = ((uint32_t)(int32_t)fl2) * P2_4;
        const uint32_t d0 = (q0 ^ (q0 + 4u))   & M4;
        const uint32_t d1 = (q1 ^ (q1 + P1_4)) & M4;
        const uint32_t d2 = (q2 ^ (q2 + P2_4)) & M4;

        uint32_t off = (q0 ^ q1 ^ q2) & M4;

        constexpr int gray[8] = {0, 1, 3, 2, 6, 7, 5, 4};
        h2 f[8];
#pragma unroll
        for (int j = 0; j < 8; ++j) {
            f[gray[j]] = *reinterpret_cast<const h2*>(tb + off);
            if (j < 7) {
                const int tog = gray[j] ^ gray[j + 1];
                off ^= (tog == 4) ? d0 : (tog == 2) ? d1 : d2;
            }
        }

        const _Float16 h0 = (_Float16)df0, h1 = (_Float16)df1, hv2 = (_Float16)df2;
        const h2 t0 = {h0, h0}, t1 = {h1, h1}, t2 = {hv2, hv2};
        h2 e0 = lerp2(f[0], f[1], t2);
        h2 e1 = lerp2(f[2], f[3], t2);
        h2 e2 = lerp2(f[4], f[5], t2);
        h2 e3 = lerp2(f[6], f[7], t2);
        h2 g0 = lerp2(e0, e1, t1);
        h2 g1 = lerp2(e2, e3, t1);
        resu.r[l] = lerp2(g0, g1, t0);

        if (l < L_LEVELS - 1) {
            h8* __restrict__ d = reinterpret_cast<h8*>(sm.tab[(l + 1) & 1]);
            h8 w0 = { (_Float16)sa0.x, (_Float16)sa0.y, (_Float16)sa0.z, (_Float16)sa0.w,
                      (_Float16)sb0.x, (_Float16)sb0.y, (_Float16)sb0.z, (_Float16)sb0.w };
            h8 w1 = { (_Float16)sa1.x, (_Float16)sa1.y, (_Float16)sa1.z, (_Float16)sa1.w,
                      (_Float16)sb1.x, (_Float16)sb1.y, (_Float16)sb1.z, (_Float16)sb1.w };
            h8 w2 = { (_Float16)sa2.x, (_Float16)sa2.y, (_Float16)sa2.z, (_Float16)sa2.w,
                      (_Float16)sb2.x, (_Float16)sb2.y, (_Float16)sb2.z, (_Float16)sb2.w };
            h8 w3 = { (_Float16)sa3.x, (_Float16)sa3.y, (_Float16)sa3.z, (_Float16)sa3.w,
                      (_Float16)sb3.x, (_Float16)sb3.y, (_Float16)sb3.z, (_Float16)sb3.w };
            d[j0] = w0;
            d[j1] = w1;
            d[j2] = w2;
            d[j3] = w3;
            __syncthreads();
        }
    }

    __syncthreads();
#pragma unroll
    for (int g = 0; g < 4; ++g)
        *reinterpret_cast<h8*>(&sm.tr[t][4 * g]) = resu.q[g];
    __syncthreads();

    float4* __restrict__ o = out + (size_t)blockIdx.x * 8192;
#pragma unroll
    for (int i = 0; i < 8; ++i) {
        const int p  = i * 128 + (t >> 3);
        const int l0 = 2 * (t & 7);
        h4 v = *reinterpret_cast<const h4*>(&sm.tr[p][l0]);
        o[i * 1024 + t] = make_float4((float)v.x, (float)v.y,
                                      (float)v.z, (float)v.w);
    }
}

extern "C" void kernel_launch(void* const* d_in, const int* in_sizes, int n_in,
                              void* d_out, int out_size, void* d_ws, size_t ws_size,
                              hipStream_t stream) {
    const float* x   = (const float*)d_in[0];
    const float* emb = (const float*)d_in[1];

    const size_t tbl_bytes = (size_t)L_LEVELS * T_SIZE * sizeof(h2); // 1 MiB

    if (ws_size >= tbl_bytes) {
        h2* tbl = (h2*)d_ws;
        cvt_tables<<<256, 256, 0, stream>>>(emb, tbl);
        hash_encode_dma<<<256, 1024, 0, stream>>>(x, tbl, (float4*)d_out);
    } else {
        hash_encode_fused<<<256, 1024, 0, stream>>>(x, emb, (float4*)d_out);
    }
}